// Round 9
// baseline (7392.673 us; speedup 1.0000x reference)
//
#include <hip/hip_runtime.h>
#include <math.h>

// Problem dims (fixed)
#define NN 1024   // nodes
#define BB 32     // batch
#define TTT 12    // time steps
#define HH 64     // hidden
#define DD 16     // embed

__device__ __forceinline__ float dot4f(const float4 v, const float* __restrict__ wv) {
    return v.x * wv[0] + v.y * wv[1] + v.z * wv[2] + v.w * wv[3];
}

__device__ __forceinline__ float sigmoidf_(float x) { return 1.0f / (1.0f + expf(-x)); }

// ---------------- A = softmax(relu(E E^T), axis=1) ----------------
__global__ __launch_bounds__(256) void compute_A_kernel(const float* __restrict__ E,
                                                        float* __restrict__ A) {
    int n = blockIdx.x;
    int tid = threadIdx.x;
    __shared__ float en[DD];
    __shared__ float red[256];
    if (tid < DD) en[tid] = E[n * DD + tid];
    __syncthreads();
    float s[4];
    float lmax = 0.0f;
    #pragma unroll
    for (int it = 0; it < 4; ++it) {
        int m = tid + it * 256;
        float acc = 0.0f;
        #pragma unroll
        for (int d = 0; d < DD; ++d) acc += en[d] * E[m * DD + d];
        acc = fmaxf(acc, 0.0f);
        s[it] = acc;
        lmax = fmaxf(lmax, acc);
    }
    red[tid] = lmax; __syncthreads();
    for (int st = 128; st > 0; st >>= 1) {
        if (tid < st) red[tid] = fmaxf(red[tid], red[tid + st]);
        __syncthreads();
    }
    float mx = red[0];
    __syncthreads();
    float lsum = 0.0f;
    #pragma unroll
    for (int it = 0; it < 4; ++it) { s[it] = expf(s[it] - mx); lsum += s[it]; }
    red[tid] = lsum; __syncthreads();
    for (int st = 128; st > 0; st >>= 1) {
        if (tid < st) red[tid] += red[tid + st];
        __syncthreads();
    }
    float inv = 1.0f / red[0];
    #pragma unroll
    for (int it = 0; it < 4; ++it) {
        int m = tid + it * 256;
        A[n * NN + m] = s[it] * inv;
    }
}

// -------- scalar gen (biases only, setup): out[n][j] = sum_d E[n][d]*Wp[d][j] ----
__global__ __launch_bounds__(256) void gen_w_f32_kernel(const float* __restrict__ E,
                                                        const float* __restrict__ Wp,
                                                        float* __restrict__ out,
                                                        int rowlen, int total) {
    int idx = blockIdx.x * 256 + threadIdx.x;
    if (idx >= total) return;
    int n = idx / rowlen;
    int j = idx - n * rowlen;
    const float* e = E + n * DD;
    float acc = 0.0f;
    #pragma unroll
    for (int d = 0; d < DD; ++d) acc += e[d] * Wp[d * rowlen + j];
    out[idx] = acc;
}

// -------- xTm[m][t*32+b] = x[b][t][m]  (x is [B,T,N,1]) --------
__global__ __launch_bounds__(256) void transpose_x_kernel(const float* __restrict__ x,
                                                          float* __restrict__ xTm) {
    int idx = blockIdx.x * 256 + threadIdx.x; // total 1024*384
    int m = idx / (TTT * BB);
    int tb = idx - m * (TTT * BB);
    int t = tb >> 5;
    int b = tb & 31;
    xTm[idx] = x[(b * TTT + t) * NN + m];
}

// -------- C[N][cols] = A[N][N] @ S[N][cols]; 64x64 tiles, 4x4 micro ----
// double-buffered LDS: ONE barrier per K-tile
__global__ __launch_bounds__(256) void diffuse_gemm(const float* __restrict__ A,
                                                    const float* __restrict__ S,
                                                    float* __restrict__ C, int cols) {
    __shared__ alignas(16) float As[2][16][68];
    __shared__ alignas(16) float Bs[2][16][64];
    const int tid = threadIdx.x;
    const int tx = tid & 15, ty = tid >> 4;
    const int rowbase = blockIdx.y * 64, colbase = blockIdx.x * 64;
    const int kl = tid & 15, r0 = (tid >> 4) * 4;
    const int ml = tid >> 6, cl = tid & 63;
    float pa[4], pb[4];
    #pragma unroll
    for (int r = 0; r < 4; ++r)
        pa[r] = A[(size_t)(rowbase + r0 + r) * NN + kl];
    #pragma unroll
    for (int mm = 0; mm < 4; ++mm)
        pb[mm] = S[(size_t)(ml + mm * 4) * cols + colbase + cl];
    #pragma unroll
    for (int r = 0; r < 4; ++r) As[0][kl][r0 + r] = pa[r];
    #pragma unroll
    for (int mm = 0; mm < 4; ++mm) Bs[0][ml + mm * 4][cl] = pb[mm];
    __syncthreads();
    int cur = 0;
    float acc[4][4] = {};
    for (int kt = 0; kt < NN; kt += 16) {
        int kn = kt + 16;
        if (kn < NN) {
            #pragma unroll
            for (int r = 0; r < 4; ++r)
                pa[r] = A[(size_t)(rowbase + r0 + r) * NN + kn + kl];
            #pragma unroll
            for (int mm = 0; mm < 4; ++mm)
                pb[mm] = S[(size_t)(kn + ml + mm * 4) * cols + colbase + cl];
        }
        #pragma unroll
        for (int kk = 0; kk < 16; ++kk) {
            float4 a = *(const float4*)&As[cur][kk][ty * 4];
            float4 b = *(const float4*)&Bs[cur][kk][tx * 4];
            acc[0][0] += a.x * b.x; acc[0][1] += a.x * b.y; acc[0][2] += a.x * b.z; acc[0][3] += a.x * b.w;
            acc[1][0] += a.y * b.x; acc[1][1] += a.y * b.y; acc[1][2] += a.y * b.z; acc[1][3] += a.y * b.w;
            acc[2][0] += a.z * b.x; acc[2][1] += a.z * b.y; acc[2][2] += a.z * b.z; acc[2][3] += a.z * b.w;
            acc[3][0] += a.w * b.x; acc[3][1] += a.w * b.y; acc[3][2] += a.w * b.z; acc[3][3] += a.w * b.w;
        }
        if (kn < NN) {
            int nxt = cur ^ 1;
            #pragma unroll
            for (int r = 0; r < 4; ++r) As[nxt][kl][r0 + r] = pa[r];
            #pragma unroll
            for (int mm = 0; mm < 4; ++mm) Bs[nxt][ml + mm * 4][cl] = pb[mm];
            __syncthreads();
            cur = nxt;
        }
    }
    #pragma unroll
    for (int i = 0; i < 4; ++i) {
        float4 v = make_float4(acc[i][0], acc[i][1], acc[i][2], acc[i][3]);
        *(float4*)&C[(size_t)(rowbase + ty * 4 + i) * cols + colbase + tx * 4] = v;
    }
}

// ================= FUSED gate/cand kernels (small-phase variants) ==========
// W[n] generated on the fly into small LDS tiles (32 input-rows per phase;
// x-row handled separately) to raise occupancy. Accumulation order per output
// is unchanged: x-term first (per k), then input rows ascending, k0 then k1.

// -------- layer1 gate: Wp4 row stride 4160; k-pool 2080; row=32 f4 ---------
__global__ __launch_bounds__(256) void l1_gate_fused(int t,
        const float* __restrict__ xTm, const float* __restrict__ AxA,
        const float* __restrict__ h1, const float* __restrict__ Ah1,
        const float* __restrict__ E, const float4* __restrict__ Wp4,
        const float* __restrict__ Bg,
        float* __restrict__ zh, float* __restrict__ rb) {
    int n = blockIdx.x, tid = threadIdx.x;
    __shared__ float en[DD];
    __shared__ alignas(16) float Wx[2 * 128];     // x-row, both k
    __shared__ alignas(16) float Wl[32 * 128];    // 16 KB phase tile
    __shared__ alignas(16) float S0[BB * HH];     // h1
    __shared__ alignas(16) float S1[BB * HH];     // Ah1
    __shared__ float sx[BB], sax[BB];
    if (tid < DD) en[tid] = E[n * DD + tid];
    for (int i = tid; i < BB * HH; i += 256) {
        S0[i] = h1[(size_t)n * (BB * HH) + i];
        S1[i] = Ah1[(size_t)n * (BB * HH) + i];
    }
    if (tid < BB) sx[tid] = xTm[n * (TTT * BB) + t * BB + tid];
    else if (tid < 2 * BB) sax[tid - BB] = AxA[n * (TTT * BB) + t * BB + (tid - BB)];
    __syncthreads();
    if (tid < 64) { // x-row: 2 k-pools x 32 float4
        int k = tid >> 5, idx = tid & 31;
        float4 a = make_float4(0.f, 0.f, 0.f, 0.f);
        #pragma unroll
        for (int d = 0; d < DD; ++d) {
            float ed = en[d];
            float4 w = Wp4[(size_t)d * 4160 + k * 2080 + idx];
            a.x += ed * w.x; a.y += ed * w.y; a.z += ed * w.z; a.w += ed * w.w;
        }
        *(float4*)&Wx[k * 128 + idx * 4] = a;
    }
    const int o = tid & 63, bq = tid >> 6;
    float accA[8], accB[8];
    float biasA = Bg[n * 128 + o], biasB = Bg[n * 128 + 64 + o];
    #pragma unroll
    for (int j = 0; j < 8; ++j) { accA[j] = biasA; accB[j] = biasB; }
    for (int p = 0; p < 4; ++p) {
        int k = p >> 1, half = p & 1;
        #pragma unroll
        for (int it = 0; it < 4; ++it) {
            int idx = tid + it * 256; // 0..1023 (32 rows x 32 f4)
            float4 a = make_float4(0.f, 0.f, 0.f, 0.f);
            #pragma unroll
            for (int d = 0; d < DD; ++d) {
                float ed = en[d];
                float4 w = Wp4[(size_t)d * 4160 + k * 2080 + (1 + half * 32) * 32 + idx];
                a.x += ed * w.x; a.y += ed * w.y; a.z += ed * w.z; a.w += ed * w.w;
            }
            *(float4*)&Wl[idx * 4] = a;
        }
        __syncthreads();
        const float* S = (k == 0) ? S0 : S1;
        if (half == 0) {
            float wxa = Wx[k * 128 + o], wxb = Wx[k * 128 + 64 + o];
            #pragma unroll
            for (int j = 0; j < 8; ++j) {
                int b = bq * 8 + j;
                float xv = (k == 0) ? sx[b] : sax[b];
                accA[j] += xv * wxa; accB[j] += xv * wxb;
            }
        }
        int ibase = half * 32;
        for (int i = 0; i < 32; i += 4) {
            float wa[4], wb[4];
            #pragma unroll
            for (int q = 0; q < 4; ++q) {
                wa[q] = Wl[(i + q) * 128 + o];
                wb[q] = Wl[(i + q) * 128 + 64 + o];
            }
            #pragma unroll
            for (int j = 0; j < 8; ++j) {
                int b = bq * 8 + j;
                float4 sv = *(const float4*)&S[b * HH + ibase + i];
                accA[j] += dot4f(sv, wa); accB[j] += dot4f(sv, wb);
            }
        }
        __syncthreads();
    }
    #pragma unroll
    for (int j = 0; j < 8; ++j) {
        int b = bq * 8 + j;
        float z = sigmoidf_(accA[j]);
        float r = sigmoidf_(accB[j]);
        zh[(size_t)n * (BB * HH) + b * HH + o] = z * S0[b * HH + o];
        rb[(size_t)n * (BB * HH) + b * HH + o] = r;
    }
}

// -------- layer1 candidate: Wp4 row stride 2080; k-pool 1040; row=16 f4 ----
__global__ __launch_bounds__(256) void l1_cand_fused(int t,
        const float* __restrict__ xTm, const float* __restrict__ AxA,
        const float* __restrict__ zhb, const float* __restrict__ azh,
        const float* __restrict__ E, const float4* __restrict__ Wp4,
        const float* __restrict__ Bc,
        const float* __restrict__ rb, float* __restrict__ h1) {
    int n = blockIdx.x, tid = threadIdx.x;
    __shared__ float en[DD];
    __shared__ alignas(16) float Wx[2 * 64];
    __shared__ alignas(16) float Wl[32 * 64];     // 8 KB
    __shared__ alignas(16) float S0[BB * HH];
    __shared__ alignas(16) float S1[BB * HH];
    __shared__ float sx[BB], sax[BB];
    if (tid < DD) en[tid] = E[n * DD + tid];
    for (int i = tid; i < BB * HH; i += 256) {
        S0[i] = zhb[(size_t)n * (BB * HH) + i];
        S1[i] = azh[(size_t)n * (BB * HH) + i];
    }
    if (tid < BB) sx[tid] = xTm[n * (TTT * BB) + t * BB + tid];
    else if (tid < 2 * BB) sax[tid - BB] = AxA[n * (TTT * BB) + t * BB + (tid - BB)];
    __syncthreads();
    if (tid < 32) { // x-row: 2 k-pools x 16 f4
        int k = tid >> 4, idx = tid & 15;
        float4 a = make_float4(0.f, 0.f, 0.f, 0.f);
        #pragma unroll
        for (int d = 0; d < DD; ++d) {
            float ed = en[d];
            float4 w = Wp4[(size_t)d * 2080 + k * 1040 + idx];
            a.x += ed * w.x; a.y += ed * w.y; a.z += ed * w.z; a.w += ed * w.w;
        }
        *(float4*)&Wx[k * 64 + idx * 4] = a;
    }
    const int o = tid & 63, bq = tid >> 6;
    float acc[8];
    float bias = Bc[n * 64 + o];
    #pragma unroll
    for (int j = 0; j < 8; ++j) acc[j] = bias;
    for (int p = 0; p < 4; ++p) {
        int k = p >> 1, half = p & 1;
        #pragma unroll
        for (int it = 0; it < 2; ++it) {
            int idx = tid + it * 256; // 0..511
            float4 a = make_float4(0.f, 0.f, 0.f, 0.f);
            #pragma unroll
            for (int d = 0; d < DD; ++d) {
                float ed = en[d];
                float4 w = Wp4[(size_t)d * 2080 + k * 1040 + (1 + half * 32) * 16 + idx];
                a.x += ed * w.x; a.y += ed * w.y; a.z += ed * w.z; a.w += ed * w.w;
            }
            *(float4*)&Wl[idx * 4] = a;
        }
        __syncthreads();
        const float* S = (k == 0) ? S0 : S1;
        if (half == 0) {
            float wx = Wx[k * 64 + o];
            #pragma unroll
            for (int j = 0; j < 8; ++j) {
                int b = bq * 8 + j;
                float xv = (k == 0) ? sx[b] : sax[b];
                acc[j] += xv * wx;
            }
        }
        int ibase = half * 32;
        for (int i = 0; i < 32; i += 4) {
            float wa[4];
            #pragma unroll
            for (int q = 0; q < 4; ++q) wa[q] = Wl[(i + q) * 64 + o];
            #pragma unroll
            for (int j = 0; j < 8; ++j) {
                int b = bq * 8 + j;
                float4 sv = *(const float4*)&S[b * HH + ibase + i];
                acc[j] += dot4f(sv, wa);
            }
        }
        __syncthreads();
    }
    #pragma unroll
    for (int j = 0; j < 8; ++j) {
        int b = bq * 8 + j;
        size_t idx = (size_t)n * (BB * HH) + b * HH + o;
        float hc = tanhf(acc[j]);
        float r = rb[idx];
        float hold = h1[idx];
        h1[idx] = r * hold + (1.0f - r) * hc;
    }
}

// -------- layer2 gate: Wp4 row stride 8192; k-pool 4096; row=32 f4 ---------
// 8 phases: k = p>>2, q = p&3 (q>>1 selects h1/h2 input, q&1 row-half)
__global__ __launch_bounds__(256) void l2_gate_fused(
        const float* __restrict__ h1, const float* __restrict__ Ah1,
        const float* __restrict__ h2, const float* __restrict__ Ah2,
        const float* __restrict__ E, const float4* __restrict__ Wp4,
        const float* __restrict__ Bg,
        float* __restrict__ zh, float* __restrict__ rb) {
    int n = blockIdx.x, tid = threadIdx.x;
    __shared__ float en[DD];
    __shared__ alignas(16) float Wl[32 * 128];   // 16 KB
    __shared__ alignas(16) float Sl[4][BB * HH]; // h1,h2,Ah1,Ah2
    if (tid < DD) en[tid] = E[n * DD + tid];
    for (int i = tid; i < BB * HH; i += 256) {
        size_t base = (size_t)n * (BB * HH) + i;
        Sl[0][i] = h1[base]; Sl[1][i] = h2[base];
        Sl[2][i] = Ah1[base]; Sl[3][i] = Ah2[base];
    }
    __syncthreads();
    const int o = tid & 63, bq = tid >> 6;
    float accA[8], accB[8];
    float biasA = Bg[n * 128 + o], biasB = Bg[n * 128 + 64 + o];
    #pragma unroll
    for (int j = 0; j < 8; ++j) { accA[j] = biasA; accB[j] = biasB; }
    for (int p = 0; p < 8; ++p) {
        int k = p >> 2, q = p & 3;
        #pragma unroll
        for (int it = 0; it < 4; ++it) {
            int idx = tid + it * 256; // 0..1023
            float4 a = make_float4(0.f, 0.f, 0.f, 0.f);
            #pragma unroll
            for (int d = 0; d < DD; ++d) {
                float ed = en[d];
                float4 w = Wp4[(size_t)d * 8192 + k * 4096 + q * 1024 + idx];
                a.x += ed * w.x; a.y += ed * w.y; a.z += ed * w.z; a.w += ed * w.w;
            }
            *(float4*)&Wl[idx * 4] = a;
        }
        __syncthreads();
        const float* S = Sl[k * 2 + (q >> 1)];
        int ibase = (q & 1) * 32;
        for (int i = 0; i < 32; i += 4) {
            float wa[4], wb[4];
            #pragma unroll
            for (int qq = 0; qq < 4; ++qq) {
                wa[qq] = Wl[(i + qq) * 128 + o];
                wb[qq] = Wl[(i + qq) * 128 + 64 + o];
            }
            #pragma unroll
            for (int j = 0; j < 8; ++j) {
                int b = bq * 8 + j;
                float4 sv = *(const float4*)&S[b * HH + ibase + i];
                accA[j] += dot4f(sv, wa); accB[j] += dot4f(sv, wb);
            }
        }
        __syncthreads();
    }
    #pragma unroll
    for (int j = 0; j < 8; ++j) {
        int b = bq * 8 + j;
        float z = sigmoidf_(accA[j]);
        float r = sigmoidf_(accB[j]);
        zh[(size_t)n * (BB * HH) + b * HH + o] = z * Sl[1][b * HH + o];
        rb[(size_t)n * (BB * HH) + b * HH + o] = r;
    }
}

// -------- layer2 candidate: Wp4 row stride 4096; k-pool 2048; row=16 f4 ----
__global__ __launch_bounds__(256) void l2_cand_fused(
        const float* __restrict__ h1, const float* __restrict__ Ah1,
        const float* __restrict__ zhb, const float* __restrict__ azh,
        const float* __restrict__ E, const float4* __restrict__ Wp4,
        const float* __restrict__ Bc,
        const float* __restrict__ rb, float* __restrict__ h2) {
    int n = blockIdx.x, tid = threadIdx.x;
    __shared__ float en[DD];
    __shared__ alignas(16) float Wl[32 * 64];    // 8 KB
    __shared__ alignas(16) float Sl[4][BB * HH]; // h1, zh, Ah1, Azh
    if (tid < DD) en[tid] = E[n * DD + tid];
    for (int i = tid; i < BB * HH; i += 256) {
        size_t base = (size_t)n * (BB * HH) + i;
        Sl[0][i] = h1[base];  Sl[1][i] = zhb[base];
        Sl[2][i] = Ah1[base]; Sl[3][i] = azh[base];
    }
    __syncthreads();
    const int o = tid & 63, bq = tid >> 6;
    float acc[8];
    float bias = Bc[n * 64 + o];
    #pragma unroll
    for (int j = 0; j < 8; ++j) acc[j] = bias;
    for (int p = 0; p < 8; ++p) {
        int k = p >> 2, q = p & 3;
        #pragma unroll
        for (int it = 0; it < 2; ++it) {
            int idx = tid + it * 256; // 0..511
            float4 a = make_float4(0.f, 0.f, 0.f, 0.f);
            #pragma unroll
            for (int d = 0; d < DD; ++d) {
                float ed = en[d];
                float4 w = Wp4[(size_t)d * 4096 + k * 2048 + q * 512 + idx];
                a.x += ed * w.x; a.y += ed * w.y; a.z += ed * w.z; a.w += ed * w.w;
            }
            *(float4*)&Wl[idx * 4] = a;
        }
        __syncthreads();
        const float* S = Sl[k * 2 + (q >> 1)];
        int ibase = (q & 1) * 32;
        for (int i = 0; i < 32; i += 4) {
            float wa[4];
            #pragma unroll
            for (int qq = 0; qq < 4; ++qq) wa[qq] = Wl[(i + qq) * 64 + o];
            #pragma unroll
            for (int j = 0; j < 8; ++j) {
                int b = bq * 8 + j;
                float4 sv = *(const float4*)&S[b * HH + ibase + i];
                acc[j] += dot4f(sv, wa);
            }
        }
        __syncthreads();
    }
    #pragma unroll
    for (int j = 0; j < 8; ++j) {
        int b = bq * 8 + j;
        size_t idx = (size_t)n * (BB * HH) + b * HH + o;
        float hc = tanhf(acc[j]);
        float r = rb[idx];
        float hold = h2[idx];
        h2[idx] = r * hold + (1.0f - r) * hc;
    }
}

// -------- output: out[b][hor][n] = h2[n][b][:] . Wout[hor][:] + bout[hor] ----
__global__ __launch_bounds__(384) void out_kernel(const float* __restrict__ h2,
                                                  const float* __restrict__ Wout,
                                                  const float* __restrict__ bout,
                                                  float* __restrict__ out) {
    int n = blockIdx.x;
    int tid = threadIdx.x;
    __shared__ float shh[BB * HH];
    __shared__ float sw[TTT * HH];
    __shared__ float sb[TTT];
    for (int i = tid; i < BB * HH; i += 384) shh[i] = h2[(size_t)n * (BB * HH) + i];
    for (int i = tid; i < TTT * HH; i += 384) sw[i] = Wout[i];
    if (tid < TTT) sb[tid] = bout[tid];
    __syncthreads();
    int b = tid & 31;
    int hor = tid >> 5;
    float acc = sb[hor];
    #pragma unroll
    for (int c = 0; c < HH; ++c) acc += shh[b * HH + c] * sw[hor * HH + c];
    out[(size_t)(b * TTT + hor) * NN + n] = acc;
}

// -------- workspace-too-small beacon --------
__global__ void report_ws_kernel(float* out, float v) { out[0] = v; }

extern "C" void kernel_launch(void* const* d_in, const int* in_sizes, int n_in,
                              void* d_out, int out_size, void* d_ws, size_t ws_size,
                              hipStream_t stream) {
    const float* x    = (const float*)d_in[0];
    const float* E    = (const float*)d_in[1];
    const float* Wg1p = (const float*)d_in[2];
    const float* bg1p = (const float*)d_in[3];
    const float* Wc1p = (const float*)d_in[4];
    const float* bc1p = (const float*)d_in[5];
    const float* Wg2p = (const float*)d_in[6];
    const float* bg2p = (const float*)d_in[7];
    const float* Wc2p = (const float*)d_in[8];
    const float* bc2p = (const float*)d_in[9];
    const float* Wout = (const float*)d_in[10];
    const float* bout = (const float*)d_in[11];
    float* out = (float*)d_out;
    float* ws = (float*)d_ws;

    // ---- workspace layout (floats): no weight materialization ----
    size_t off = 0;
    float* A_   = ws + off; off += (size_t)NN * NN;
    float* B1g  = ws + off; off += (size_t)NN * 128;
    float* B1c  = ws + off; off += (size_t)NN * 64;
    float* B2g  = ws + off; off += (size_t)NN * 128;
    float* B2c  = ws + off; off += (size_t)NN * 64;
    float* xTm  = ws + off; off += (size_t)NN * TTT * BB;
    float* AxA  = ws + off; off += (size_t)NN * TTT * BB;
    const size_t ST = (size_t)NN * BB * HH;
    float* h1   = ws + off; off += ST;
    float* h2   = ws + off; off += ST;
    float* Ah1  = ws + off; off += ST;
    float* Ah2  = ws + off; off += ST;
    float* Azh  = ws + off; off += ST;
    float* ZH   = ws + off; off += ST;
    float* Rb   = ws + off; off += ST;
    size_t need_bytes = off * sizeof(float); // ~68.4 MB
    if (ws_size < need_bytes) {
        report_ws_kernel<<<1, 1, 0, stream>>>(out, (float)ws_size);
        return;
    }

    (void)hipMemsetAsync(h1, 0, ST * 4, stream);
    (void)hipMemsetAsync(h2, 0, ST * 4, stream);
    (void)hipMemsetAsync(Ah1, 0, ST * 4, stream);
    (void)hipMemsetAsync(Ah2, 0, ST * 4, stream);
    (void)hipMemsetAsync(Azh, 0, ST * 4, stream);

    // ---- setup (once) ----
    compute_A_kernel<<<NN, 256, 0, stream>>>(E, A_);
    gen_w_f32_kernel<<<(131072 + 255) / 256, 256, 0, stream>>>(E, bg1p, B1g, 128, 131072);
    gen_w_f32_kernel<<<(65536 + 255) / 256, 256, 0, stream>>>(E, bc1p, B1c, 64, 65536);
    gen_w_f32_kernel<<<(131072 + 255) / 256, 256, 0, stream>>>(E, bg2p, B2g, 128, 131072);
    gen_w_f32_kernel<<<(65536 + 255) / 256, 256, 0, stream>>>(E, bc2p, B2c, 64, 65536);
    transpose_x_kernel<<<(NN * TTT * BB) / 256, 256, 0, stream>>>(x, xTm);
    diffuse_gemm<<<dim3((TTT * BB) / 64, NN / 64), 256, 0, stream>>>(A_, xTm, AxA, TTT * BB);

    const int COLS = BB * HH; // 2048
    dim3 gemmGrid(COLS / 64, NN / 64);

    // ---- scan over time ----
    for (int t = 0; t < TTT; ++t) {
        l1_gate_fused<<<NN, 256, 0, stream>>>(t, xTm, AxA, h1, Ah1,
                                              E, (const float4*)Wg1p, B1g, ZH, Rb);
        if (t > 0) diffuse_gemm<<<gemmGrid, 256, 0, stream>>>(A_, ZH, Azh, COLS);
        l1_cand_fused<<<NN, 256, 0, stream>>>(t, xTm, AxA, ZH, Azh,
                                              E, (const float4*)Wc1p, B1c, Rb, h1);
        diffuse_gemm<<<gemmGrid, 256, 0, stream>>>(A_, h1, Ah1, COLS);
        l2_gate_fused<<<NN, 256, 0, stream>>>(h1, Ah1, h2, Ah2,
                                              E, (const float4*)Wg2p, B2g, ZH, Rb);
        if (t > 0) diffuse_gemm<<<gemmGrid, 256, 0, stream>>>(A_, ZH, Azh, COLS);
        l2_cand_fused<<<NN, 256, 0, stream>>>(h1, Ah1, ZH, Azh,
                                              E, (const float4*)Wc2p, B2c, Rb, h2);
        if (t < TTT - 1) diffuse_gemm<<<gemmGrid, 256, 0, stream>>>(A_, h2, Ah2, COLS);
    }

    out_kernel<<<NN, 384, 0, stream>>>(h2, Wout, bout, out);
}

// Round 10
// 5891.036 us; speedup vs baseline: 1.2549x; 1.2549x over previous
//
#include <hip/hip_runtime.h>
#include <math.h>

// Problem dims (fixed)
#define NN 1024   // nodes
#define BB 32     // batch
#define TTT 12    // time steps
#define HH 64     // hidden
#define DD 16     // embed

__device__ __forceinline__ float dot4f(const float4 v, const float* __restrict__ wv) {
    return v.x * wv[0] + v.y * wv[1] + v.z * wv[2] + v.w * wv[3];
}

__device__ __forceinline__ float sigmoidf_(float x) { return 1.0f / (1.0f + expf(-x)); }

// ---------------- A = softmax(relu(E E^T), axis=1) ----------------
__global__ __launch_bounds__(256) void compute_A_kernel(const float* __restrict__ E,
                                                        float* __restrict__ A) {
    int n = blockIdx.x;
    int tid = threadIdx.x;
    __shared__ float en[DD];
    __shared__ float red[256];
    if (tid < DD) en[tid] = E[n * DD + tid];
    __syncthreads();
    float s[4];
    float lmax = 0.0f;
    #pragma unroll
    for (int it = 0; it < 4; ++it) {
        int m = tid + it * 256;
        float acc = 0.0f;
        #pragma unroll
        for (int d = 0; d < DD; ++d) acc += en[d] * E[m * DD + d];
        acc = fmaxf(acc, 0.0f);
        s[it] = acc;
        lmax = fmaxf(lmax, acc);
    }
    red[tid] = lmax; __syncthreads();
    for (int st = 128; st > 0; st >>= 1) {
        if (tid < st) red[tid] = fmaxf(red[tid], red[tid + st]);
        __syncthreads();
    }
    float mx = red[0];
    __syncthreads();
    float lsum = 0.0f;
    #pragma unroll
    for (int it = 0; it < 4; ++it) { s[it] = expf(s[it] - mx); lsum += s[it]; }
    red[tid] = lsum; __syncthreads();
    for (int st = 128; st > 0; st >>= 1) {
        if (tid < st) red[tid] += red[tid + st];
        __syncthreads();
    }
    float inv = 1.0f / red[0];
    #pragma unroll
    for (int it = 0; it < 4; ++it) {
        int m = tid + it * 256;
        A[n * NN + m] = s[it] * inv;
    }
}

// -------- scalar gen (biases): out[n][j] = sum_d E[n][d]*Wp[d][j] --------
__global__ __launch_bounds__(256) void gen_w_f32_kernel(const float* __restrict__ E,
                                                        const float* __restrict__ Wp,
                                                        float* __restrict__ out,
                                                        int rowlen, int total) {
    int idx = blockIdx.x * 256 + threadIdx.x;
    if (idx >= total) return;
    int n = idx / rowlen;
    int j = idx - n * rowlen;
    const float* e = E + n * DD;
    float acc = 0.0f;
    #pragma unroll
    for (int d = 0; d < DD; ++d) acc += e[d] * Wp[d * rowlen + j];
    out[idx] = acc;
}

// -------- float4 gen (big weights, setup-time materialization) -----------
__global__ __launch_bounds__(256) void gen_w4_kernel(const float* __restrict__ E,
                                                     const float4* __restrict__ Wp4,
                                                     float4* __restrict__ out4,
                                                     int rowlen4, int total4) {
    int idx = blockIdx.x * 256 + threadIdx.x;
    if (idx >= total4) return;
    int n = idx / rowlen4;
    int j = idx - n * rowlen4;
    const float* e = E + n * DD;
    float4 acc = make_float4(0.f, 0.f, 0.f, 0.f);
    #pragma unroll
    for (int d = 0; d < DD; ++d) {
        float ed = e[d];
        float4 w = Wp4[(size_t)d * rowlen4 + j];
        acc.x += ed * w.x; acc.y += ed * w.y; acc.z += ed * w.z; acc.w += ed * w.w;
    }
    out4[idx] = acc;
}

// -------- xTm[m][t*32+b] = x[b][t][m]  (x is [B,T,N,1]) --------
__global__ __launch_bounds__(256) void transpose_x_kernel(const float* __restrict__ x,
                                                          float* __restrict__ xTm) {
    int idx = blockIdx.x * 256 + threadIdx.x; // total 1024*384
    int m = idx / (TTT * BB);
    int tb = idx - m * (TTT * BB);
    int t = tb >> 5;
    int b = tb & 31;
    xTm[idx] = x[(b * TTT + t) * NN + m];
}

// -------- C[N][cols] = A[N][N] @ S[N][cols]; 64x64 tiles, double-buffered --
__global__ __launch_bounds__(256) void diffuse_gemm(const float* __restrict__ A,
                                                    const float* __restrict__ S,
                                                    float* __restrict__ C, int cols) {
    __shared__ alignas(16) float As[2][16][68];
    __shared__ alignas(16) float Bs[2][16][64];
    const int tid = threadIdx.x;
    const int tx = tid & 15, ty = tid >> 4;
    const int rowbase = blockIdx.y * 64, colbase = blockIdx.x * 64;
    const int kl = tid & 15, r0 = (tid >> 4) * 4;
    const int ml = tid >> 6, cl = tid & 63;
    float pa[4], pb[4];
    #pragma unroll
    for (int r = 0; r < 4; ++r)
        pa[r] = A[(size_t)(rowbase + r0 + r) * NN + kl];
    #pragma unroll
    for (int mm = 0; mm < 4; ++mm)
        pb[mm] = S[(size_t)(ml + mm * 4) * cols + colbase + cl];
    #pragma unroll
    for (int r = 0; r < 4; ++r) As[0][kl][r0 + r] = pa[r];
    #pragma unroll
    for (int mm = 0; mm < 4; ++mm) Bs[0][ml + mm * 4][cl] = pb[mm];
    __syncthreads();
    int cur = 0;
    float acc[4][4] = {};
    for (int kt = 0; kt < NN; kt += 16) {
        int kn = kt + 16;
        if (kn < NN) {
            #pragma unroll
            for (int r = 0; r < 4; ++r)
                pa[r] = A[(size_t)(rowbase + r0 + r) * NN + kn + kl];
            #pragma unroll
            for (int mm = 0; mm < 4; ++mm)
                pb[mm] = S[(size_t)(kn + ml + mm * 4) * cols + colbase + cl];
        }
        #pragma unroll
        for (int kk = 0; kk < 16; ++kk) {
            float4 a = *(const float4*)&As[cur][kk][ty * 4];
            float4 b = *(const float4*)&Bs[cur][kk][tx * 4];
            acc[0][0] += a.x * b.x; acc[0][1] += a.x * b.y; acc[0][2] += a.x * b.z; acc[0][3] += a.x * b.w;
            acc[1][0] += a.y * b.x; acc[1][1] += a.y * b.y; acc[1][2] += a.y * b.z; acc[1][3] += a.y * b.w;
            acc[2][0] += a.z * b.x; acc[2][1] += a.z * b.y; acc[2][2] += a.z * b.z; acc[2][3] += a.z * b.w;
            acc[3][0] += a.w * b.x; acc[3][1] += a.w * b.y; acc[3][2] += a.w * b.z; acc[3][3] += a.w * b.w;
        }
        if (kn < NN) {
            int nxt = cur ^ 1;
            #pragma unroll
            for (int r = 0; r < 4; ++r) As[nxt][kl][r0 + r] = pa[r];
            #pragma unroll
            for (int mm = 0; mm < 4; ++mm) Bs[nxt][ml + mm * 4][cl] = pb[mm];
            __syncthreads();
            cur = nxt;
        }
    }
    #pragma unroll
    for (int i = 0; i < 4; ++i) {
        float4 v = make_float4(acc[i][0], acc[i][1], acc[i][2], acc[i][3]);
        *(float4*)&C[(size_t)(rowbase + ty * 4 + i) * cols + colbase + tx * 4] = v;
    }
}

// ======== materialized-weight consumers (weights read from HBM) ========

// -------- layer1 gate (materialized W): W layout [k(2)][i(65)][o(128)] ----
__global__ __launch_bounds__(256) void l1_gate_kernel(int t,
        const float* __restrict__ xTm, const float* __restrict__ AxA,
        const float* __restrict__ h1, const float* __restrict__ Ah1,
        const float* __restrict__ Wg, const float* __restrict__ Bg,
        float* __restrict__ zh, float* __restrict__ rb) {
    int n = blockIdx.x;
    int tid = threadIdx.x;
    __shared__ alignas(16) float sh[BB * HH];
    __shared__ alignas(16) float sa[BB * HH];
    __shared__ float sx[BB], sax[BB];
    for (int i = tid; i < BB * HH; i += 256) {
        sh[i] = h1[(size_t)n * (BB * HH) + i];
        sa[i] = Ah1[(size_t)n * (BB * HH) + i];
    }
    if (tid < BB) sx[tid] = xTm[n * (TTT * BB) + t * BB + tid];
    else if (tid < 2 * BB) sax[tid - BB] = AxA[n * (TTT * BB) + t * BB + (tid - BB)];
    __syncthreads();
    const int o = tid & 63;
    const int bq = tid >> 6;
    const float* W = Wg + (size_t)n * 16640; // 2*65*128
    float accA[8], accB[8];
    float biasA = Bg[n * 128 + o], biasB = Bg[n * 128 + 64 + o];
    float wxa0 = W[o], wxa1 = W[8320 + o];
    float wxb0 = W[64 + o], wxb1 = W[8320 + 64 + o];
    #pragma unroll
    for (int j = 0; j < 8; ++j) {
        int b = bq * 8 + j;
        accA[j] = biasA + sx[b] * wxa0 + sax[b] * wxa1;
        accB[j] = biasB + sx[b] * wxb0 + sax[b] * wxb1;
    }
    for (int i = 0; i < HH; i += 4) {
        float w0a[4], w1a[4], w0b[4], w1b[4];
        #pragma unroll
        for (int q = 0; q < 4; ++q) {
            int row = (1 + i + q) * 128;
            w0a[q] = W[row + o];            w1a[q] = W[8320 + row + o];
            w0b[q] = W[row + 64 + o];       w1b[q] = W[8320 + row + 64 + o];
        }
        #pragma unroll
        for (int j = 0; j < 8; ++j) {
            int b = bq * 8 + j;
            float4 hv = *(const float4*)&sh[b * HH + i];
            float4 av = *(const float4*)&sa[b * HH + i];
            accA[j] += dot4f(hv, w0a) + dot4f(av, w1a);
            accB[j] += dot4f(hv, w0b) + dot4f(av, w1b);
        }
    }
    #pragma unroll
    for (int j = 0; j < 8; ++j) {
        int b = bq * 8 + j;
        float z = sigmoidf_(accA[j]);
        float r = sigmoidf_(accB[j]);
        zh[(size_t)n * (BB * HH) + b * HH + o] = z * sh[b * HH + o];
        rb[(size_t)n * (BB * HH) + b * HH + o] = r;
    }
}

// -------- layer2 gate (materialized W): W [k(2)][i(128)][o(128)] --------
__global__ __launch_bounds__(256) void l2_gate_kernel(
        const float* __restrict__ h1, const float* __restrict__ Ah1,
        const float* __restrict__ h2, const float* __restrict__ Ah2,
        const float* __restrict__ Wg, const float* __restrict__ Bg,
        float* __restrict__ zh, float* __restrict__ rb) {
    int n = blockIdx.x;
    int tid = threadIdx.x;
    __shared__ alignas(16) float s1[BB * HH];
    __shared__ alignas(16) float sa1[BB * HH];
    __shared__ alignas(16) float s2[BB * HH];
    __shared__ alignas(16) float sa2[BB * HH];
    for (int i = tid; i < BB * HH; i += 256) {
        size_t base = (size_t)n * (BB * HH) + i;
        s1[i] = h1[base]; sa1[i] = Ah1[base];
        s2[i] = h2[base]; sa2[i] = Ah2[base];
    }
    __syncthreads();
    const int o = tid & 63;
    const int bq = tid >> 6;
    const float* W = Wg + (size_t)n * 32768; // 2*128*128
    float accA[8], accB[8];
    float biasA = Bg[n * 128 + o], biasB = Bg[n * 128 + 64 + o];
    #pragma unroll
    for (int j = 0; j < 8; ++j) { accA[j] = biasA; accB[j] = biasB; }
    for (int i = 0; i < HH; i += 4) {
        float w10a[4], w11a[4], w20a[4], w21a[4];
        float w10b[4], w11b[4], w20b[4], w21b[4];
        #pragma unroll
        for (int q = 0; q < 4; ++q) {
            int r1 = (i + q) * 128;
            int r2 = (64 + i + q) * 128;
            w10a[q] = W[r1 + o];          w10b[q] = W[r1 + 64 + o];
            w11a[q] = W[16384 + r1 + o];  w11b[q] = W[16384 + r1 + 64 + o];
            w20a[q] = W[r2 + o];          w20b[q] = W[r2 + 64 + o];
            w21a[q] = W[16384 + r2 + o];  w21b[q] = W[16384 + r2 + 64 + o];
        }
        #pragma unroll
        for (int j = 0; j < 8; ++j) {
            int b = bq * 8 + j;
            float4 v1 = *(const float4*)&s1[b * HH + i];
            float4 u1 = *(const float4*)&sa1[b * HH + i];
            float4 v2 = *(const float4*)&s2[b * HH + i];
            float4 u2 = *(const float4*)&sa2[b * HH + i];
            accA[j] += dot4f(v1, w10a) + dot4f(u1, w11a) + dot4f(v2, w20a) + dot4f(u2, w21a);
            accB[j] += dot4f(v1, w10b) + dot4f(u1, w11b) + dot4f(v2, w20b) + dot4f(u2, w21b);
        }
    }
    #pragma unroll
    for (int j = 0; j < 8; ++j) {
        int b = bq * 8 + j;
        float z = sigmoidf_(accA[j]);
        float r = sigmoidf_(accB[j]);
        zh[(size_t)n * (BB * HH) + b * HH + o] = z * s2[b * HH + o];
        rb[(size_t)n * (BB * HH) + b * HH + o] = r;
    }
}

// ======== fused (on-the-fly weight gen) consumers — R8 shapes ========

// -------- layer1 gate fused: Wp [16][2][65][128]; 2 phases (k) ----------
__global__ __launch_bounds__(256) void l1_gate_fused(int t,
        const float* __restrict__ xTm, const float* __restrict__ AxA,
        const float* __restrict__ h1, const float* __restrict__ Ah1,
        const float* __restrict__ E, const float4* __restrict__ Wp4,
        const float* __restrict__ Bg,
        float* __restrict__ zh, float* __restrict__ rb) {
    int n = blockIdx.x, tid = threadIdx.x;
    __shared__ float en[DD];
    __shared__ alignas(16) float Wl[65 * 128];
    __shared__ alignas(16) float S0[BB * HH];
    __shared__ alignas(16) float S1[BB * HH];
    __shared__ float sx[BB], sax[BB];
    if (tid < DD) en[tid] = E[n * DD + tid];
    for (int i = tid; i < BB * HH; i += 256) {
        S0[i] = h1[(size_t)n * (BB * HH) + i];
        S1[i] = Ah1[(size_t)n * (BB * HH) + i];
    }
    if (tid < BB) sx[tid] = xTm[n * (TTT * BB) + t * BB + tid];
    else if (tid < 2 * BB) sax[tid - BB] = AxA[n * (TTT * BB) + t * BB + (tid - BB)];
    __syncthreads();
    const int o = tid & 63, bq = tid >> 6;
    float accA[8], accB[8];
    float biasA = Bg[n * 128 + o], biasB = Bg[n * 128 + 64 + o];
    #pragma unroll
    for (int j = 0; j < 8; ++j) { accA[j] = biasA; accB[j] = biasB; }
    for (int k = 0; k < 2; ++k) {
        for (int idx = tid; idx < 2080; idx += 256) {
            float4 a = make_float4(0.f, 0.f, 0.f, 0.f);
            #pragma unroll
            for (int d = 0; d < DD; ++d) {
                float ed = en[d];
                float4 w = Wp4[(size_t)d * 4160 + k * 2080 + idx];
                a.x += ed * w.x; a.y += ed * w.y; a.z += ed * w.z; a.w += ed * w.w;
            }
            *(float4*)&Wl[idx * 4] = a;
        }
        __syncthreads();
        const float* S = (k == 0) ? S0 : S1;
        float wxa = Wl[o], wxb = Wl[64 + o];
        #pragma unroll
        for (int j = 0; j < 8; ++j) {
            int b = bq * 8 + j;
            float xv = (k == 0) ? sx[b] : sax[b];
            accA[j] += xv * wxa; accB[j] += xv * wxb;
        }
        for (int i = 0; i < HH; i += 4) {
            float wa[4], wb[4];
            #pragma unroll
            for (int q = 0; q < 4; ++q) {
                int row = (1 + i + q) * 128;
                wa[q] = Wl[row + o]; wb[q] = Wl[row + 64 + o];
            }
            #pragma unroll
            for (int j = 0; j < 8; ++j) {
                int b = bq * 8 + j;
                float4 sv = *(const float4*)&S[b * HH + i];
                accA[j] += dot4f(sv, wa); accB[j] += dot4f(sv, wb);
            }
        }
        __syncthreads();
    }
    #pragma unroll
    for (int j = 0; j < 8; ++j) {
        int b = bq * 8 + j;
        float z = sigmoidf_(accA[j]);
        float r = sigmoidf_(accB[j]);
        zh[(size_t)n * (BB * HH) + b * HH + o] = z * S0[b * HH + o];
        rb[(size_t)n * (BB * HH) + b * HH + o] = r;
    }
}

// -------- layer1 candidate fused: Wp [16][2][65][64]; 2 phases ----------
__global__ __launch_bounds__(256) void l1_cand_fused(int t,
        const float* __restrict__ xTm, const float* __restrict__ AxA,
        const float* __restrict__ zhb, const float* __restrict__ azh,
        const float* __restrict__ E, const float4* __restrict__ Wp4,
        const float* __restrict__ Bc,
        const float* __restrict__ rb, float* __restrict__ h1) {
    int n = blockIdx.x, tid = threadIdx.x;
    __shared__ float en[DD];
    __shared__ alignas(16) float Wl[65 * 64];
    __shared__ alignas(16) float S0[BB * HH];
    __shared__ alignas(16) float S1[BB * HH];
    __shared__ float sx[BB], sax[BB];
    if (tid < DD) en[tid] = E[n * DD + tid];
    for (int i = tid; i < BB * HH; i += 256) {
        S0[i] = zhb[(size_t)n * (BB * HH) + i];
        S1[i] = azh[(size_t)n * (BB * HH) + i];
    }
    if (tid < BB) sx[tid] = xTm[n * (TTT * BB) + t * BB + tid];
    else if (tid < 2 * BB) sax[tid - BB] = AxA[n * (TTT * BB) + t * BB + (tid - BB)];
    __syncthreads();
    const int o = tid & 63, bq = tid >> 6;
    float acc[8];
    float bias = Bc[n * 64 + o];
    #pragma unroll
    for (int j = 0; j < 8; ++j) acc[j] = bias;
    for (int k = 0; k < 2; ++k) {
        for (int idx = tid; idx < 1040; idx += 256) {
            float4 a = make_float4(0.f, 0.f, 0.f, 0.f);
            #pragma unroll
            for (int d = 0; d < DD; ++d) {
                float ed = en[d];
                float4 w = Wp4[(size_t)d * 2080 + k * 1040 + idx];
                a.x += ed * w.x; a.y += ed * w.y; a.z += ed * w.z; a.w += ed * w.w;
            }
            *(float4*)&Wl[idx * 4] = a;
        }
        __syncthreads();
        const float* S = (k == 0) ? S0 : S1;
        float wx = Wl[o];
        #pragma unroll
        for (int j = 0; j < 8; ++j) {
            int b = bq * 8 + j;
            float xv = (k == 0) ? sx[b] : sax[b];
            acc[j] += xv * wx;
        }
        for (int i = 0; i < HH; i += 4) {
            float wa[4];
            #pragma unroll
            for (int q = 0; q < 4; ++q) wa[q] = Wl[(1 + i + q) * 64 + o];
            #pragma unroll
            for (int j = 0; j < 8; ++j) {
                int b = bq * 8 + j;
                float4 sv = *(const float4*)&S[b * HH + i];
                acc[j] += dot4f(sv, wa);
            }
        }
        __syncthreads();
    }
    #pragma unroll
    for (int j = 0; j < 8; ++j) {
        int b = bq * 8 + j;
        size_t idx = (size_t)n * (BB * HH) + b * HH + o;
        float hc = tanhf(acc[j]);
        float r = rb[idx];
        float hold = h1[idx];
        h1[idx] = r * hold + (1.0f - r) * hc;
    }
}

// -------- layer2 candidate fused: Wp [16][2][128][64]; 4 phases ---------
__global__ __launch_bounds__(256) void l2_cand_fused(
        const float* __restrict__ h1, const float* __restrict__ Ah1,
        const float* __restrict__ zhb, const float* __restrict__ azh,
        const float* __restrict__ E, const float4* __restrict__ Wp4,
        const float* __restrict__ Bc,
        const float* __restrict__ rb, float* __restrict__ h2) {
    int n = blockIdx.x, tid = threadIdx.x;
    __shared__ float en[DD];
    __shared__ alignas(16) float Wl[64 * 64];
    __shared__ alignas(16) float Sl[4][BB * HH]; // h1, zh, Ah1, Azh
    if (tid < DD) en[tid] = E[n * DD + tid];
    for (int i = tid; i < BB * HH; i += 256) {
        size_t base = (size_t)n * (BB * HH) + i;
        Sl[0][i] = h1[base];  Sl[1][i] = zhb[base];
        Sl[2][i] = Ah1[base]; Sl[3][i] = azh[base];
    }
    __syncthreads();
    const int o = tid & 63, bq = tid >> 6;
    float acc[8];
    float bias = Bc[n * 64 + o];
    #pragma unroll
    for (int j = 0; j < 8; ++j) acc[j] = bias;
    for (int p = 0; p < 4; ++p) {
        int k = p >> 1, half = p & 1;
        for (int idx = tid; idx < 1024; idx += 256) {
            float4 a = make_float4(0.f, 0.f, 0.f, 0.f);
            #pragma unroll
            for (int d = 0; d < DD; ++d) {
                float ed = en[d];
                float4 w = Wp4[(size_t)d * 4096 + k * 2048 + half * 1024 + idx];
                a.x += ed * w.x; a.y += ed * w.y; a.z += ed * w.z; a.w += ed * w.w;
            }
            *(float4*)&Wl[idx * 4] = a;
        }
        __syncthreads();
        const float* S = Sl[k * 2 + half];
        for (int i = 0; i < HH; i += 4) {
            float wa[4];
            #pragma unroll
            for (int qq = 0; qq < 4; ++qq) wa[qq] = Wl[(i + qq) * 64 + o];
            #pragma unroll
            for (int j = 0; j < 8; ++j) {
                int b = bq * 8 + j;
                float4 sv = *(const float4*)&S[b * HH + i];
                acc[j] += dot4f(sv, wa);
            }
        }
        __syncthreads();
    }
    #pragma unroll
    for (int j = 0; j < 8; ++j) {
        int b = bq * 8 + j;
        size_t idx = (size_t)n * (BB * HH) + b * HH + o;
        float hc = tanhf(acc[j]);
        float r = rb[idx];
        float hold = h2[idx];
        h2[idx] = r * hold + (1.0f - r) * hc;
    }
}

// -------- output: out[b][hor][n] = h2[n][b][:] . Wout[hor][:] + bout[hor] ----
__global__ __launch_bounds__(384) void out_kernel(const float* __restrict__ h2,
                                                  const float* __restrict__ Wout,
                                                  const float* __restrict__ bout,
                                                  float* __restrict__ out) {
    int n = blockIdx.x;
    int tid = threadIdx.x;
    __shared__ float shh[BB * HH];
    __shared__ float sw[TTT * HH];
    __shared__ float sb[TTT];
    for (int i = tid; i < BB * HH; i += 384) shh[i] = h2[(size_t)n * (BB * HH) + i];
    for (int i = tid; i < TTT * HH; i += 384) sw[i] = Wout[i];
    if (tid < TTT) sb[tid] = bout[tid];
    __syncthreads();
    int b = tid & 31;
    int hor = tid >> 5;
    float acc = sb[hor];
    #pragma unroll
    for (int c = 0; c < HH; ++c) acc += shh[b * HH + c] * sw[hor * HH + c];
    out[(size_t)(b * TTT + hor) * NN + n] = acc;
}

// -------- workspace-too-small beacon --------
__global__ void report_ws_kernel(float* out, float v) { out[0] = v; }

extern "C" void kernel_launch(void* const* d_in, const int* in_sizes, int n_in,
                              void* d_out, int out_size, void* d_ws, size_t ws_size,
                              hipStream_t stream) {
    const float* x    = (const float*)d_in[0];
    const float* E    = (const float*)d_in[1];
    const float* Wg1p = (const float*)d_in[2];
    const float* bg1p = (const float*)d_in[3];
    const float* Wc1p = (const float*)d_in[4];
    const float* bc1p = (const float*)d_in[5];
    const float* Wg2p = (const float*)d_in[6];
    const float* bg2p = (const float*)d_in[7];
    const float* Wc2p = (const float*)d_in[8];
    const float* bc2p = (const float*)d_in[9];
    const float* Wout = (const float*)d_in[10];
    const float* bout = (const float*)d_in[11];
    float* out = (float*)d_out;
    float* ws = (float*)d_ws;

    // ---- workspace: states + static W2g (guaranteed), optional static W1g ----
    size_t off = 0;
    float* A_   = ws + off; off += (size_t)NN * NN;
    float* B1g  = ws + off; off += (size_t)NN * 128;
    float* B1c  = ws + off; off += (size_t)NN * 64;
    float* B2g  = ws + off; off += (size_t)NN * 128;
    float* B2c  = ws + off; off += (size_t)NN * 64;
    float* xTm  = ws + off; off += (size_t)NN * TTT * BB;
    float* AxA  = ws + off; off += (size_t)NN * TTT * BB;
    const size_t ST = (size_t)NN * BB * HH;
    float* h1   = ws + off; off += ST;
    float* h2   = ws + off; off += ST;
    float* Ah1  = ws + off; off += ST;
    float* Ah2  = ws + off; off += ST;
    float* Azh  = ws + off; off += ST;
    float* ZH   = ws + off; off += ST;
    float* Rb   = ws + off; off += ST;
    float* W2G  = ws + off; off += (size_t)NN * 32768;      // static fp32 W2g
    size_t need_w2g = off * sizeof(float);                  // ~202.6 MB (fits: ws>=220)
    float* W1G  = ws + off;                                 // optional static W1g
    size_t need_w1g = need_w2g + (size_t)NN * 16640 * sizeof(float); // ~270.8 MB
    if (ws_size < need_w2g) {
        report_ws_kernel<<<1, 1, 0, stream>>>(out, (float)ws_size);
        return;
    }
    const bool w1g_static = (ws_size >= need_w1g); // deterministic -> graph-safe

    (void)hipMemsetAsync(h1, 0, ST * 4, stream);
    (void)hipMemsetAsync(h2, 0, ST * 4, stream);
    (void)hipMemsetAsync(Ah1, 0, ST * 4, stream);
    (void)hipMemsetAsync(Ah2, 0, ST * 4, stream);
    (void)hipMemsetAsync(Azh, 0, ST * 4, stream);

    // ---- setup (once) ----
    compute_A_kernel<<<NN, 256, 0, stream>>>(E, A_);
    gen_w_f32_kernel<<<(131072 + 255) / 256, 256, 0, stream>>>(E, bg1p, B1g, 128, 131072);
    gen_w_f32_kernel<<<(65536 + 255) / 256, 256, 0, stream>>>(E, bc1p, B1c, 64, 65536);
    gen_w_f32_kernel<<<(131072 + 255) / 256, 256, 0, stream>>>(E, bg2p, B2g, 128, 131072);
    gen_w_f32_kernel<<<(65536 + 255) / 256, 256, 0, stream>>>(E, bc2p, B2c, 64, 65536);
    transpose_x_kernel<<<(NN * TTT * BB) / 256, 256, 0, stream>>>(x, xTm);
    diffuse_gemm<<<dim3((TTT * BB) / 64, NN / 64), 256, 0, stream>>>(A_, xTm, AxA, TTT * BB);
    gen_w4_kernel<<<(8388608 + 255) / 256, 256, 0, stream>>>(
        E, (const float4*)Wg2p, (float4*)W2G, 8192, 8388608);
    if (w1g_static) {
        gen_w4_kernel<<<(4259840 + 255) / 256, 256, 0, stream>>>(
            E, (const float4*)Wg1p, (float4*)W1G, 4160, 4259840);
    }

    const int COLS = BB * HH; // 2048
    dim3 gemmGrid(COLS / 64, NN / 64);

    // ---- scan over time ----
    for (int t = 0; t < TTT; ++t) {
        if (w1g_static)
            l1_gate_kernel<<<NN, 256, 0, stream>>>(t, xTm, AxA, h1, Ah1, W1G, B1g, ZH, Rb);
        else
            l1_gate_fused<<<NN, 256, 0, stream>>>(t, xTm, AxA, h1, Ah1,
                                                  E, (const float4*)Wg1p, B1g, ZH, Rb);
        if (t > 0) diffuse_gemm<<<gemmGrid, 256, 0, stream>>>(A_, ZH, Azh, COLS);
        l1_cand_fused<<<NN, 256, 0, stream>>>(t, xTm, AxA, ZH, Azh,
                                              E, (const float4*)Wc1p, B1c, Rb, h1);
        diffuse_gemm<<<gemmGrid, 256, 0, stream>>>(A_, h1, Ah1, COLS);
        l2_gate_kernel<<<NN, 256, 0, stream>>>(h1, Ah1, h2, Ah2, W2G, B2g, ZH, Rb);
        if (t > 0) diffuse_gemm<<<gemmGrid, 256, 0, stream>>>(A_, ZH, Azh, COLS);
        l2_cand_fused<<<NN, 256, 0, stream>>>(h1, Ah1, ZH, Azh,
                                              E, (const float4*)Wc2p, B2c, Rb, h2);
        if (t < TTT - 1) diffuse_gemm<<<gemmGrid, 256, 0, stream>>>(A_, h2, Ah2, COLS);
    }

    out_kernel<<<NN, 384, 0, stream>>>(h2, Wout, bout, out);
}